// Round 5
// baseline (404.166 us; speedup 1.0000x reference)
//
#include <hip/hip_runtime.h>
#include <cstdint>
#include <cstddef>

#define N_NODES 100000
#define N_EDGES 1600000
#define N_GRAPHS 256
#define HID 128
#define NCLASS 8

#define SCHUNK 2048
#define SNB ((N_NODES + SCHUNK - 1) / SCHUNK)  // 49

static __device__ __forceinline__ float lrelu(float x) { return x >= 0.f ? x : 0.2f * x; }
static __device__ __forceinline__ float elu_f(float x) { return x > 0.f ? x : expm1f(x); }
static __device__ __forceinline__ unsigned f2bf(float x) {  // RNE bf16 (as uint16 in low bits)
    union { float f; unsigned u; } v; v.f = x;
    return (v.u + 0x7FFFu + ((v.u >> 16) & 1u)) >> 16;
}
static __device__ __forceinline__ float bf_lo(unsigned u) { return __uint_as_float(u << 16); }
static __device__ __forceinline__ float bf_hi(unsigned u) { return __uint_as_float(u & 0xFFFF0000u); }

// --- K1: cl1 = W1·al1, cr1 = W1·ar1 (layer-1 rank-1 collapse) ---
__global__ void k_prep(const float* __restrict__ W1, const float* __restrict__ al1,
                       const float* __restrict__ ar1, float* __restrict__ scal) {
    int l = threadIdx.x;  // 64 threads
    float pl = W1[l] * al1[l] + W1[l + 64] * al1[l + 64];
    float pr = W1[l] * ar1[l] + W1[l + 64] * ar1[l + 64];
    for (int m = 32; m >= 1; m >>= 1) { pl += __shfl_xor(pl, m); pr += __shfl_xor(pr, m); }
    if (l == 0) { scal[0] = pl; scal[1] = pr; }
}

// --- K2: degree count into 8 privatized replicas + per-edge rank (ONE atomic pass) ---
__global__ void k_degrank(const int* __restrict__ dst, int* __restrict__ dr,
                          int* __restrict__ rank) {
    int i = blockIdx.x * blockDim.x + threadIdx.x;
    int st = gridDim.x * blockDim.x;
    for (; i < N_EDGES; i += st) {
        int cls = (i >> 8) & (NCLASS - 1);
        rank[i] = atomicAdd(&dr[cls * N_NODES + dst[i]], 1);
    }
}

// --- K2b: total degree = sum of replicas ---
__global__ void k_sum(const int* __restrict__ dr, int* __restrict__ deg) {
    int d = blockIdx.x * blockDim.x + threadIdx.x;
    if (d < N_NODES) {
        int s = 0;
#pragma unroll
        for (int r = 0; r < NCLASS; r++) s += dr[r * N_NODES + d];
        deg[d] = s;
    }
}

// --- K3: exclusive scan of deg -> offsets ---
__global__ void k_scan_part(const int* __restrict__ deg, int* __restrict__ P) {
    __shared__ int sh[256];
    int base = blockIdx.x * SCHUNK + threadIdx.x * 8;
    int s = 0;
#pragma unroll
    for (int e = 0; e < 8; e++) { int idx = base + e; if (idx < N_NODES) s += deg[idx]; }
    sh[threadIdx.x] = s; __syncthreads();
    for (int d = 128; d >= 1; d >>= 1) {
        if (threadIdx.x < d) sh[threadIdx.x] += sh[threadIdx.x + d];
        __syncthreads();
    }
    if (threadIdx.x == 0) P[blockIdx.x] = sh[0];
}

__global__ void k_scan_p2(const int* __restrict__ P, int* __restrict__ P2, int* __restrict__ offs) {
    if (threadIdx.x == 0) {
        int run = 0;
        for (int b = 0; b < SNB; b++) { P2[b] = run; run += P[b]; }
        offs[N_NODES] = run;
    }
}

__global__ void k_scan_final(const int* __restrict__ deg, const int* __restrict__ P2,
                             int* __restrict__ offs) {
    __shared__ int sh[256];
    int base = blockIdx.x * SCHUNK + threadIdx.x * 8;
    int loc[8]; int s = 0;
#pragma unroll
    for (int e = 0; e < 8; e++) {
        int idx = base + e;
        loc[e] = (idx < N_NODES) ? deg[idx] : 0;
        s += loc[e];
    }
    int own = s;
    sh[threadIdx.x] = s; __syncthreads();
    for (int d = 1; d < 256; d <<= 1) {
        int v = (threadIdx.x >= (unsigned)d) ? sh[threadIdx.x - d] : 0;
        __syncthreads();
        sh[threadIdx.x] += v;
        __syncthreads();
    }
    int run = P2[blockIdx.x] + sh[threadIdx.x] - own;
#pragma unroll
    for (int e = 0; e < 8; e++) {
        int idx = base + e;
        if (idx < N_NODES) { offs[idx] = run; run += loc[e]; }
    }
}

// --- K3b: per-class base offsets ---
__global__ void k_base(const int* __restrict__ dr, const int* __restrict__ offs,
                       int* __restrict__ base) {
    int d = blockIdx.x * blockDim.x + threadIdx.x;
    if (d < N_NODES) {
        int run = offs[d];
#pragma unroll
        for (int r = 0; r < NCLASS; r++) { base[r * N_NODES + d] = run; run += dr[r * N_NODES + d]; }
    }
}

// --- K4: CSR fill — NO atomics ---
__global__ void k_fill(const int* __restrict__ src, const int* __restrict__ dst,
                       const int* __restrict__ base, const int* __restrict__ rank,
                       int* __restrict__ csr) {
    int i = blockIdx.x * blockDim.x + threadIdx.x;
    int st = gridDim.x * blockDim.x;
    for (; i < N_EDGES; i += st) {
        int cls = (i >> 8) & (NCLASS - 1);
        int pos = base[cls * N_NODES + dst[i]] + rank[i];
        csr[pos] = src[i];
    }
}

// --- K5: layer-1 attention -> t[i] (wave per node, lane-parallel edges) ---
__global__ __launch_bounds__(256) void k_l1(const int* __restrict__ deg, const int* __restrict__ offs,
                                            const int* __restrict__ csr_src, const float* __restrict__ scal,
                                            float* __restrict__ t) {
    int node = blockIdx.x * 4 + (threadIdx.x >> 6);
    if (node >= N_NODES) return;
    int l = threadIdx.x & 63;
    float cl = scal[0], cr = scal[1];
    float eri = cr * (float)deg[node];
    int off = offs[node], end = offs[node + 1];
    float m = -INFINITY, den = 0.f, num = 0.f;
    for (int e = off + l; e < end; e += 64) {
        int s = csr_src[e];
        float ds = (float)deg[s];
        float e1 = lrelu(cl * ds + eri);
        if (e1 > m) { float c = __expf(m - e1); den *= c; num *= c; m = e1; }
        float w = __expf(e1 - m);
        den += w; num += w * ds;
    }
    for (int st = 1; st < 64; st <<= 1) {
        float mo = __shfl_xor(m, st);
        float dn = __shfl_xor(den, st);
        float no = __shfl_xor(num, st);
        float mn = fmaxf(m, mo);
        float sa = (m  > -1e37f) ? __expf(m  - mn) : 0.f;
        float sb = (mo > -1e37f) ? __expf(mo - mn) : 0.f;
        den = den * sa + dn * sb;
        num = num * sa + no * sb;
        m = mn;
    }
    if (l == 0) t[node] = num / fmaxf(den, 1e-9f);
}

// --- K6: z2 = elu(t*W1+b1) @ W2 (bf16 out) ; el2/er2 from fp32 acc ---
// 8 groups x 32 lanes; 8 nodes per group; k-unroll 4 -> ds_read_b128 broadcast h reads.
// launch_bounds(256,4): 4 blocks/CU (LDS 34KB*4=136KB), VGPR cap 128.
__global__ __launch_bounds__(256, 4) void k_gemm(
    const float* __restrict__ t, const float* __restrict__ W1, const float* __restrict__ b1,
    const float* __restrict__ W2, const float* __restrict__ al2, const float* __restrict__ ar2,
    unsigned* __restrict__ zb, float* __restrict__ el2, float* __restrict__ er2) {
    __shared__ float h1s[8][8][HID];
    __shared__ float W1s[HID], b1s[HID], al2s[HID], ar2s[HID];
    if (threadIdx.x < HID) {
        W1s[threadIdx.x] = W1[threadIdx.x]; b1s[threadIdx.x] = b1[threadIdx.x];
        al2s[threadIdx.x] = al2[threadIdx.x]; ar2s[threadIdx.x] = ar2[threadIdx.x];
    }
    __syncthreads();
    int g = threadIdx.x >> 5;
    int lt = threadIdx.x & 31;
    const float4* W2v = (const float4*)W2;
    for (int i0 = blockIdx.x * 64; i0 < N_NODES; i0 += gridDim.x * 64) {
        int ibase = i0 + g * 8;
        for (int n = 0; n < 8; n++) {
            int i = ibase + n;
            if (i < N_NODES) {
                float ti = t[i];
                float4 hv;
                hv.x = elu_f(ti * W1s[4 * lt + 0] + b1s[4 * lt + 0]);
                hv.y = elu_f(ti * W1s[4 * lt + 1] + b1s[4 * lt + 1]);
                hv.z = elu_f(ti * W1s[4 * lt + 2] + b1s[4 * lt + 2]);
                hv.w = elu_f(ti * W1s[4 * lt + 3] + b1s[4 * lt + 3]);
                *(float4*)&h1s[g][n][4 * lt] = hv;
            }
        }
        __syncthreads();
        float4 acc[8];
#pragma unroll
        for (int n = 0; n < 8; n++) acc[n] = make_float4(0.f, 0.f, 0.f, 0.f);
        for (int j = 0; j < HID / 4; j++) {  // 4 k's per iter
            float4 w0 = W2v[(4 * j + 0) * 32 + lt];
            float4 w1 = W2v[(4 * j + 1) * 32 + lt];
            float4 w2 = W2v[(4 * j + 2) * 32 + lt];
            float4 w3 = W2v[(4 * j + 3) * 32 + lt];
#pragma unroll
            for (int n = 0; n < 8; n++) {
                float4 hv = *(const float4*)&h1s[g][n][4 * j];  // b128 broadcast
                acc[n].x += hv.x * w0.x + hv.y * w1.x + hv.z * w2.x + hv.w * w3.x;
                acc[n].y += hv.x * w0.y + hv.y * w1.y + hv.z * w2.y + hv.w * w3.y;
                acc[n].z += hv.x * w0.z + hv.y * w1.z + hv.z * w2.z + hv.w * w3.z;
                acc[n].w += hv.x * w0.w + hv.y * w1.w + hv.z * w2.w + hv.w * w3.w;
            }
        }
#pragma unroll
        for (int n = 0; n < 8; n++) {
            int i = ibase + n;
            if (i < N_NODES) {
                float4 a = acc[n];
                uint2 st;
                st.x = f2bf(a.x) | (f2bf(a.y) << 16);
                st.y = f2bf(a.z) | (f2bf(a.w) << 16);
                *(uint2*)&zb[(size_t)i * 64 + 2 * lt] = st;
                float pl = a.x * al2s[4 * lt] + a.y * al2s[4 * lt + 1] +
                           a.z * al2s[4 * lt + 2] + a.w * al2s[4 * lt + 3];
                float pr = a.x * ar2s[4 * lt] + a.y * ar2s[4 * lt + 1] +
                           a.z * ar2s[4 * lt + 2] + a.w * ar2s[4 * lt + 3];
                for (int mm = 16; mm >= 1; mm >>= 1) { pl += __shfl_xor(pl, mm); pr += __shfl_xor(pr, mm); }
                if (lt == 0) { el2[i] = pl; er2[i] = pr; }
            }
        }
        __syncthreads();
    }
}

// --- K7: FUSED layer-2 attention + aggregation (one wave per node) ---
// pass 1: lane-parallel (m, den) + shuffle merge; pass 2: per-edge inline weight
// (el2[s] broadcast, L1-hot) + coalesced bf16x2 zb gather, 4x unrolled.
__global__ __launch_bounds__(256) void k_l2f(
    const int* __restrict__ offs, const int* __restrict__ csr_src,
    const float* __restrict__ el2, const float* __restrict__ er2,
    const unsigned* __restrict__ zb, const float* __restrict__ b2,
    float* __restrict__ h2) {
    int node = blockIdx.x * 4 + (threadIdx.x >> 6);
    if (node >= N_NODES) return;
    int l = threadIdx.x & 63;
    float eri = er2[node];
    int off = offs[node], end = offs[node + 1];
    float m = -INFINITY, den = 0.f;
    for (int e = off + l; e < end; e += 64) {
        int s = csr_src[e];
        float x = el2[s] + eri;
        float e2 = x >= 0.f ? x : 0.2f * x;
        if (e2 > m) { den *= __expf(m - e2); m = e2; }
        den += __expf(e2 - m);
    }
    for (int st = 1; st < 64; st <<= 1) {
        float mo = __shfl_xor(m, st);
        float dn = __shfl_xor(den, st);
        float mn = fmaxf(m, mo);
        float sa = (m  > -1e37f) ? __expf(m  - mn) : 0.f;
        float sb = (mo > -1e37f) ? __expf(mo - mn) : 0.f;
        den = den * sa + dn * sb;
        m = mn;
    }
    float rden = 1.f / fmaxf(den, 1e-9f);
    float a0 = 0.f, a1 = 0.f;
    int e = off;
    for (; e + 4 <= end; e += 4) {
        int s0 = csr_src[e], s1 = csr_src[e + 1], s2 = csr_src[e + 2], s3 = csr_src[e + 3];
        float x0 = el2[s0] + eri, x1 = el2[s1] + eri, x2 = el2[s2] + eri, x3 = el2[s3] + eri;
        float w0 = __expf(lrelu(x0) - m) * rden;
        float w1 = __expf(lrelu(x1) - m) * rden;
        float w2 = __expf(lrelu(x2) - m) * rden;
        float w3 = __expf(lrelu(x3) - m) * rden;
        unsigned z0 = zb[(size_t)s0 * 64 + l];
        unsigned z1 = zb[(size_t)s1 * 64 + l];
        unsigned z2 = zb[(size_t)s2 * 64 + l];
        unsigned z3 = zb[(size_t)s3 * 64 + l];
        a0 += w0 * bf_lo(z0) + w1 * bf_lo(z1) + w2 * bf_lo(z2) + w3 * bf_lo(z3);
        a1 += w0 * bf_hi(z0) + w1 * bf_hi(z1) + w2 * bf_hi(z2) + w3 * bf_hi(z3);
    }
    for (; e < end; e++) {
        int s = csr_src[e];
        float x = el2[s] + eri;
        float w = __expf(lrelu(x) - m) * rden;
        unsigned z = zb[(size_t)s * 64 + l];
        a0 += w * bf_lo(z);
        a1 += w * bf_hi(z);
    }
    float2 bb = *(const float2*)&b2[2 * l];
    float2 o;
    o.x = elu_f(a0 + bb.x);
    o.y = elu_f(a1 + bb.y);
    *(float2*)&h2[(size_t)node * HID + 2 * l] = o;
}

// --- K8: mean-pool + classifier ---
static __device__ __forceinline__ int lower_bound_i(const int* a, int n, int v) {
    int lo = 0, hi = n;
    while (lo < hi) { int mid = (lo + hi) >> 1; if (a[mid] < v) lo = mid + 1; else hi = mid; }
    return lo;
}

__global__ __launch_bounds__(1024) void k_pool(const int* __restrict__ gids, const float* __restrict__ h2,
                                               const float* __restrict__ Wc, const float* __restrict__ bc,
                                               float* __restrict__ out) {
    int g = blockIdx.x;
    int lo = lower_bound_i(gids, N_NODES, g);
    int hi = lower_bound_i(gids, N_NODES, g + 1);
    int j = threadIdx.x & 127;   // feature
    int nn = threadIdx.x >> 7;   // node-slot 0..7
    float s = 0.f;
    for (int n = lo + nn; n < hi; n += 8) s += h2[(size_t)n * HID + j];
    __shared__ float red[1024];
    red[threadIdx.x] = s;
    __syncthreads();
    __shared__ float red2[2][3];
    if (threadIdx.x < 128) {
        float hg = 0.f;
#pragma unroll
        for (int q = 0; q < 8; q++) hg += red[q * 128 + j];
        hg /= fmaxf((float)(hi - lo), 1.f);
        float p0 = hg * Wc[j * 3 + 0];
        float p1 = hg * Wc[j * 3 + 1];
        float p2 = hg * Wc[j * 3 + 2];
        for (int mm = 32; mm >= 1; mm >>= 1) {
            p0 += __shfl_xor(p0, mm); p1 += __shfl_xor(p1, mm); p2 += __shfl_xor(p2, mm);
        }
        if ((threadIdx.x & 63) == 0) {
            int w = threadIdx.x >> 6;
            red2[w][0] = p0; red2[w][1] = p1; red2[w][2] = p2;
        }
    }
    __syncthreads();
    if (threadIdx.x < 3)
        out[g * 3 + threadIdx.x] = red2[0][threadIdx.x] + red2[1][threadIdx.x] + bc[threadIdx.x];
}

extern "C" void kernel_launch(void* const* d_in, const int* in_sizes, int n_in,
                              void* d_out, int out_size, void* d_ws, size_t ws_size,
                              hipStream_t stream) {
    (void)in_sizes; (void)n_in; (void)out_size; (void)ws_size;
    const int* edge_src = (const int*)d_in[0];
    const int* edge_dst = (const int*)d_in[1];
    const int* gids     = (const int*)d_in[2];
    const float* W1  = (const float*)d_in[3];
    const float* al1 = (const float*)d_in[4];
    const float* ar1 = (const float*)d_in[5];
    const float* b1  = (const float*)d_in[6];
    const float* W2  = (const float*)d_in[7];
    const float* al2 = (const float*)d_in[8];
    const float* ar2 = (const float*)d_in[9];
    const float* b2  = (const float*)d_in[10];
    const float* Wc  = (const float*)d_in[11];
    const float* bc  = (const float*)d_in[12];
    float* out = (float*)d_out;

    char* p = (char*)d_ws;
    auto alloc = [&](size_t bytes) -> char* {
        char* r = p;
        p += (bytes + 511) & ~(size_t)511;
        return r;
    };
    int*      dr    = (int*)alloc((size_t)NCLASS * N_NODES * 4);   // privatized counters
    int*      base  = (int*)alloc((size_t)NCLASS * N_NODES * 4);   // per-class CSR bases
    int*      rank  = (int*)alloc((size_t)N_EDGES * 4);            // per-edge within-class rank
    int*      offs  = (int*)alloc((size_t)(N_NODES + 1) * 4);
    int*      P     = (int*)alloc((size_t)SNB * 4);
    int*      P2    = (int*)alloc((size_t)SNB * 4);
    float*    scal  = (float*)alloc(64);
    int*      csr   = (int*)alloc((size_t)N_EDGES * 4);
    int*      deg   = (int*)alloc((size_t)N_NODES * 4);
    float*    t     = (float*)alloc((size_t)N_NODES * 4);
    float*    el2   = (float*)alloc((size_t)N_NODES * 4);
    float*    er2   = (float*)alloc((size_t)N_NODES * 4);
    unsigned* zb    = (unsigned*)alloc((size_t)N_NODES * 64 * 4);  // bf16x2 packed
    float*    h2    = (float*)alloc((size_t)N_NODES * HID * 4);

    hipMemsetAsync(dr, 0, (size_t)NCLASS * N_NODES * 4, stream);

    k_prep<<<1, 64, 0, stream>>>(W1, al1, ar1, scal);
    k_degrank<<<2048, 256, 0, stream>>>(edge_dst, dr, rank);
    k_sum<<<(N_NODES + 255) / 256, 256, 0, stream>>>(dr, deg);
    k_scan_part<<<SNB, 256, 0, stream>>>(deg, P);
    k_scan_p2<<<1, 64, 0, stream>>>(P, P2, offs);
    k_scan_final<<<SNB, 256, 0, stream>>>(deg, P2, offs);
    k_base<<<(N_NODES + 255) / 256, 256, 0, stream>>>(dr, offs, base);
    k_fill<<<2048, 256, 0, stream>>>(edge_src, edge_dst, base, rank, csr);
    k_l1<<<(N_NODES + 3) / 4, 256, 0, stream>>>(deg, offs, csr, scal, t);
    k_gemm<<<(N_NODES + 63) / 64, 256, 0, stream>>>(t, W1, b1, W2, al2, ar2, zb, el2, er2);
    k_l2f<<<(N_NODES + 3) / 4, 256, 0, stream>>>(offs, csr, el2, er2, zb, b2, h2);
    k_pool<<<N_GRAPHS, 1024, 0, stream>>>(gids, h2, Wc, bc, out);
}

// Round 6
// 382.599 us; speedup vs baseline: 1.0564x; 1.0564x over previous
//
#include <hip/hip_runtime.h>
#include <cstdint>
#include <cstddef>

#define N_NODES 100000
#define N_EDGES 1600000
#define N_GRAPHS 256
#define HID 128
#define NCLASS 8
#define MAXD 128  // LDS-staged edges per node (max in-degree ~45 for this input; tails handled inline)

#define SCHUNK 2048
#define SNB ((N_NODES + SCHUNK - 1) / SCHUNK)  // 49

static __device__ __forceinline__ float lrelu(float x) { return x >= 0.f ? x : 0.2f * x; }
static __device__ __forceinline__ float elu_f(float x) { return x > 0.f ? x : expm1f(x); }
static __device__ __forceinline__ unsigned f2bf(float x) {  // RNE bf16 (as uint16 in low bits)
    union { float f; unsigned u; } v; v.f = x;
    return (v.u + 0x7FFFu + ((v.u >> 16) & 1u)) >> 16;
}
static __device__ __forceinline__ float bf_lo(unsigned u) { return __uint_as_float(u << 16); }
static __device__ __forceinline__ float bf_hi(unsigned u) { return __uint_as_float(u & 0xFFFF0000u); }

// --- K1: cl1 = W1·al1, cr1 = W1·ar1 (layer-1 rank-1 collapse) ---
__global__ void k_prep(const float* __restrict__ W1, const float* __restrict__ al1,
                       const float* __restrict__ ar1, float* __restrict__ scal) {
    int l = threadIdx.x;  // 64 threads
    float pl = W1[l] * al1[l] + W1[l + 64] * al1[l + 64];
    float pr = W1[l] * ar1[l] + W1[l + 64] * ar1[l + 64];
    for (int m = 32; m >= 1; m >>= 1) { pl += __shfl_xor(pl, m); pr += __shfl_xor(pr, m); }
    if (l == 0) { scal[0] = pl; scal[1] = pr; }
}

// --- K2: degree count into 8 privatized replicas + per-edge rank (ONE atomic pass) ---
__global__ void k_degrank(const int* __restrict__ dst, int* __restrict__ dr,
                          int* __restrict__ rank) {
    int i = blockIdx.x * blockDim.x + threadIdx.x;
    int st = gridDim.x * blockDim.x;
    for (; i < N_EDGES; i += st) {
        int cls = (i >> 8) & (NCLASS - 1);
        rank[i] = atomicAdd(&dr[cls * N_NODES + dst[i]], 1);
    }
}

// --- K2b: total degree = sum of replicas ---
__global__ void k_sum(const int* __restrict__ dr, int* __restrict__ deg) {
    int d = blockIdx.x * blockDim.x + threadIdx.x;
    if (d < N_NODES) {
        int s = 0;
#pragma unroll
        for (int r = 0; r < NCLASS; r++) s += dr[r * N_NODES + d];
        deg[d] = s;
    }
}

// --- K3: exclusive scan of deg -> offsets ---
__global__ void k_scan_part(const int* __restrict__ deg, int* __restrict__ P) {
    __shared__ int sh[256];
    int base = blockIdx.x * SCHUNK + threadIdx.x * 8;
    int s = 0;
#pragma unroll
    for (int e = 0; e < 8; e++) { int idx = base + e; if (idx < N_NODES) s += deg[idx]; }
    sh[threadIdx.x] = s; __syncthreads();
    for (int d = 128; d >= 1; d >>= 1) {
        if (threadIdx.x < d) sh[threadIdx.x] += sh[threadIdx.x + d];
        __syncthreads();
    }
    if (threadIdx.x == 0) P[blockIdx.x] = sh[0];
}

__global__ void k_scan_p2(const int* __restrict__ P, int* __restrict__ P2, int* __restrict__ offs) {
    if (threadIdx.x == 0) {
        int run = 0;
        for (int b = 0; b < SNB; b++) { P2[b] = run; run += P[b]; }
        offs[N_NODES] = run;
    }
}

__global__ void k_scan_final(const int* __restrict__ deg, const int* __restrict__ P2,
                             int* __restrict__ offs) {
    __shared__ int sh[256];
    int base = blockIdx.x * SCHUNK + threadIdx.x * 8;
    int loc[8]; int s = 0;
#pragma unroll
    for (int e = 0; e < 8; e++) {
        int idx = base + e;
        loc[e] = (idx < N_NODES) ? deg[idx] : 0;
        s += loc[e];
    }
    int own = s;
    sh[threadIdx.x] = s; __syncthreads();
    for (int d = 1; d < 256; d <<= 1) {
        int v = (threadIdx.x >= (unsigned)d) ? sh[threadIdx.x - d] : 0;
        __syncthreads();
        sh[threadIdx.x] += v;
        __syncthreads();
    }
    int run = P2[blockIdx.x] + sh[threadIdx.x] - own;
#pragma unroll
    for (int e = 0; e < 8; e++) {
        int idx = base + e;
        if (idx < N_NODES) { offs[idx] = run; run += loc[e]; }
    }
}

// --- K3b: per-class base offsets ---
__global__ void k_base(const int* __restrict__ dr, const int* __restrict__ offs,
                       int* __restrict__ base) {
    int d = blockIdx.x * blockDim.x + threadIdx.x;
    if (d < N_NODES) {
        int run = offs[d];
#pragma unroll
        for (int r = 0; r < NCLASS; r++) { base[r * N_NODES + d] = run; run += dr[r * N_NODES + d]; }
    }
}

// --- K4: CSR fill — NO atomics ---
__global__ void k_fill(const int* __restrict__ src, const int* __restrict__ dst,
                       const int* __restrict__ base, const int* __restrict__ rank,
                       int* __restrict__ csr) {
    int i = blockIdx.x * blockDim.x + threadIdx.x;
    int st = gridDim.x * blockDim.x;
    for (; i < N_EDGES; i += st) {
        int cls = (i >> 8) & (NCLASS - 1);
        int pos = base[cls * N_NODES + dst[i]] + rank[i];
        csr[pos] = src[i];
    }
}

// --- K5: layer-1 attention -> t[i] (wave per node, lane-parallel edges) ---
__global__ __launch_bounds__(256) void k_l1(const int* __restrict__ deg, const int* __restrict__ offs,
                                            const int* __restrict__ csr_src, const float* __restrict__ scal,
                                            float* __restrict__ t) {
    int node = blockIdx.x * 4 + (threadIdx.x >> 6);
    if (node >= N_NODES) return;
    int l = threadIdx.x & 63;
    float cl = scal[0], cr = scal[1];
    float eri = cr * (float)deg[node];
    int off = offs[node], end = offs[node + 1];
    float m = -INFINITY, den = 0.f, num = 0.f;
    for (int e = off + l; e < end; e += 64) {
        int s = csr_src[e];
        float ds = (float)deg[s];
        float e1 = lrelu(cl * ds + eri);
        if (e1 > m) { float c = __expf(m - e1); den *= c; num *= c; m = e1; }
        float w = __expf(e1 - m);
        den += w; num += w * ds;
    }
    for (int st = 1; st < 64; st <<= 1) {
        float mo = __shfl_xor(m, st);
        float dn = __shfl_xor(den, st);
        float no = __shfl_xor(num, st);
        float mn = fmaxf(m, mo);
        float sa = (m  > -1e37f) ? __expf(m  - mn) : 0.f;
        float sb = (mo > -1e37f) ? __expf(mo - mn) : 0.f;
        den = den * sa + dn * sb;
        num = num * sa + no * sb;
        m = mn;
    }
    if (l == 0) t[node] = num / fmaxf(den, 1e-9f);
}

// --- K6: z2 = elu(t*W1+b1) @ W2 (bf16 out) ; el2/er2 from fp32 acc ---
__global__ __launch_bounds__(256, 4) void k_gemm(
    const float* __restrict__ t, const float* __restrict__ W1, const float* __restrict__ b1,
    const float* __restrict__ W2, const float* __restrict__ al2, const float* __restrict__ ar2,
    unsigned* __restrict__ zb, float* __restrict__ el2, float* __restrict__ er2) {
    __shared__ float h1s[8][8][HID];
    __shared__ float W1s[HID], b1s[HID], al2s[HID], ar2s[HID];
    if (threadIdx.x < HID) {
        W1s[threadIdx.x] = W1[threadIdx.x]; b1s[threadIdx.x] = b1[threadIdx.x];
        al2s[threadIdx.x] = al2[threadIdx.x]; ar2s[threadIdx.x] = ar2[threadIdx.x];
    }
    __syncthreads();
    int g = threadIdx.x >> 5;
    int lt = threadIdx.x & 31;
    const float4* W2v = (const float4*)W2;
    for (int i0 = blockIdx.x * 64; i0 < N_NODES; i0 += gridDim.x * 64) {
        int ibase = i0 + g * 8;
        for (int n = 0; n < 8; n++) {
            int i = ibase + n;
            if (i < N_NODES) {
                float ti = t[i];
                float4 hv;
                hv.x = elu_f(ti * W1s[4 * lt + 0] + b1s[4 * lt + 0]);
                hv.y = elu_f(ti * W1s[4 * lt + 1] + b1s[4 * lt + 1]);
                hv.z = elu_f(ti * W1s[4 * lt + 2] + b1s[4 * lt + 2]);
                hv.w = elu_f(ti * W1s[4 * lt + 3] + b1s[4 * lt + 3]);
                *(float4*)&h1s[g][n][4 * lt] = hv;
            }
        }
        __syncthreads();
        float4 acc[8];
#pragma unroll
        for (int n = 0; n < 8; n++) acc[n] = make_float4(0.f, 0.f, 0.f, 0.f);
        for (int j = 0; j < HID / 4; j++) {  // 4 k's per iter
            float4 w0 = W2v[(4 * j + 0) * 32 + lt];
            float4 w1 = W2v[(4 * j + 1) * 32 + lt];
            float4 w2 = W2v[(4 * j + 2) * 32 + lt];
            float4 w3 = W2v[(4 * j + 3) * 32 + lt];
#pragma unroll
            for (int n = 0; n < 8; n++) {
                float4 hv = *(const float4*)&h1s[g][n][4 * j];  // b128 broadcast
                acc[n].x += hv.x * w0.x + hv.y * w1.x + hv.z * w2.x + hv.w * w3.x;
                acc[n].y += hv.x * w0.y + hv.y * w1.y + hv.z * w2.y + hv.w * w3.y;
                acc[n].z += hv.x * w0.z + hv.y * w1.z + hv.z * w2.z + hv.w * w3.z;
                acc[n].w += hv.x * w0.w + hv.y * w1.w + hv.z * w2.w + hv.w * w3.w;
            }
        }
#pragma unroll
        for (int n = 0; n < 8; n++) {
            int i = ibase + n;
            if (i < N_NODES) {
                float4 a = acc[n];
                uint2 st;
                st.x = f2bf(a.x) | (f2bf(a.y) << 16);
                st.y = f2bf(a.z) | (f2bf(a.w) << 16);
                *(uint2*)&zb[(size_t)i * 64 + 2 * lt] = st;
                float pl = a.x * al2s[4 * lt] + a.y * al2s[4 * lt + 1] +
                           a.z * al2s[4 * lt + 2] + a.w * al2s[4 * lt + 3];
                float pr = a.x * ar2s[4 * lt] + a.y * ar2s[4 * lt + 1] +
                           a.z * ar2s[4 * lt + 2] + a.w * ar2s[4 * lt + 3];
                for (int mm = 16; mm >= 1; mm >>= 1) { pl += __shfl_xor(pl, mm); pr += __shfl_xor(pr, mm); }
                if (lt == 0) { el2[i] = pl; er2[i] = pr; }
            }
        }
        __syncthreads();
    }
}

// --- K7: FUSED layer-2 attention + aggregation, LDS-staged weights ---
// ph1 (lane-parallel): e2 -> LDS, shuffle-max. ph2 (lane-parallel): w=exp(e2-m) in
// place, shuffle-sum den. ph3: broadcast ds_read_b128 of (w4,s4) + coalesced zb
// gather; normalize accumulator ONCE by 1/den. All LDS deps are same-wave.
__global__ __launch_bounds__(256) void k_l2f(
    const int* __restrict__ offs, const int* __restrict__ csr_src,
    const float* __restrict__ el2, const float* __restrict__ er2,
    const unsigned* __restrict__ zb, const float* __restrict__ b2,
    float* __restrict__ h2) {
    __shared__ float wbuf[4][MAXD];
    __shared__ int   sbuf[4][MAXD];
    int wv = threadIdx.x >> 6;
    int node = blockIdx.x * 4 + wv;
    if (node >= N_NODES) return;
    int l = threadIdx.x & 63;
    float eri = er2[node];
    int off = offs[node], end = offs[node + 1];
    int deg = end - off;
    int ndeg = min(deg, MAXD);
    // ph1: stage s,e2; lane-max over ALL edges
    float mx = -INFINITY;
    for (int j = l; j < deg; j += 64) {
        int s = csr_src[off + j];
        float x = el2[s] + eri;
        float e2 = lrelu(x);
        if (j < MAXD) { sbuf[wv][j] = s; wbuf[wv][j] = e2; }
        mx = fmaxf(mx, e2);
    }
    for (int st = 1; st < 64; st <<= 1) mx = fmaxf(mx, __shfl_xor(mx, st));
    // ph2: w = exp(e2-mx) in place; den
    float den = 0.f;
    for (int j = l; j < ndeg; j += 64) {
        float w = __expf(wbuf[wv][j] - mx);
        wbuf[wv][j] = w;
        den += w;
    }
    for (int j = MAXD + l; j < deg; j += 64) {  // tail beyond LDS cap (never in practice)
        int s = csr_src[off + j];
        den += __expf(lrelu(el2[s] + eri) - mx);
    }
    for (int st = 1; st < 64; st <<= 1) den += __shfl_xor(den, st);
    float rden = 1.f / fmaxf(den, 1e-9f);
    // ph3: weighted gather
    float a0 = 0.f, a1 = 0.f;
    int j = 0;
    for (; j + 4 <= ndeg; j += 4) {
        float4 w4 = *(const float4*)&wbuf[wv][j];  // broadcast ds_read_b128
        int4   s4 = *(const int4*)&sbuf[wv][j];    // broadcast ds_read_b128
        unsigned z0 = zb[((unsigned)s4.x << 6) + l];
        unsigned z1 = zb[((unsigned)s4.y << 6) + l];
        unsigned z2 = zb[((unsigned)s4.z << 6) + l];
        unsigned z3 = zb[((unsigned)s4.w << 6) + l];
        a0 += w4.x * bf_lo(z0) + w4.y * bf_lo(z1) + w4.z * bf_lo(z2) + w4.w * bf_lo(z3);
        a1 += w4.x * bf_hi(z0) + w4.y * bf_hi(z1) + w4.z * bf_hi(z2) + w4.w * bf_hi(z3);
    }
    for (; j < ndeg; j++) {
        float w = wbuf[wv][j];
        unsigned z = zb[((unsigned)sbuf[wv][j] << 6) + l];
        a0 += w * bf_lo(z);
        a1 += w * bf_hi(z);
    }
    for (int j2 = MAXD; j2 < deg; j2++) {  // tail beyond LDS cap (never in practice)
        int s = csr_src[off + j2];
        float w = __expf(lrelu(el2[s] + eri) - mx);
        unsigned z = zb[((unsigned)s << 6) + l];
        a0 += w * bf_lo(z);
        a1 += w * bf_hi(z);
    }
    float2 bb = *(const float2*)&b2[2 * l];
    float2 o;
    o.x = elu_f(a0 * rden + bb.x);
    o.y = elu_f(a1 * rden + bb.y);
    *(float2*)&h2[(size_t)node * HID + 2 * l] = o;
}

// --- K8: mean-pool + classifier ---
static __device__ __forceinline__ int lower_bound_i(const int* a, int n, int v) {
    int lo = 0, hi = n;
    while (lo < hi) { int mid = (lo + hi) >> 1; if (a[mid] < v) lo = mid + 1; else hi = mid; }
    return lo;
}

__global__ __launch_bounds__(1024) void k_pool(const int* __restrict__ gids, const float* __restrict__ h2,
                                               const float* __restrict__ Wc, const float* __restrict__ bc,
                                               float* __restrict__ out) {
    int g = blockIdx.x;
    int lo = lower_bound_i(gids, N_NODES, g);
    int hi = lower_bound_i(gids, N_NODES, g + 1);
    int j = threadIdx.x & 127;   // feature
    int nn = threadIdx.x >> 7;   // node-slot 0..7
    float s = 0.f;
    for (int n = lo + nn; n < hi; n += 8) s += h2[(size_t)n * HID + j];
    __shared__ float red[1024];
    red[threadIdx.x] = s;
    __syncthreads();
    __shared__ float red2[2][3];
    if (threadIdx.x < 128) {
        float hg = 0.f;
#pragma unroll
        for (int q = 0; q < 8; q++) hg += red[q * 128 + j];
        hg /= fmaxf((float)(hi - lo), 1.f);
        float p0 = hg * Wc[j * 3 + 0];
        float p1 = hg * Wc[j * 3 + 1];
        float p2 = hg * Wc[j * 3 + 2];
        for (int mm = 32; mm >= 1; mm >>= 1) {
            p0 += __shfl_xor(p0, mm); p1 += __shfl_xor(p1, mm); p2 += __shfl_xor(p2, mm);
        }
        if ((threadIdx.x & 63) == 0) {
            int w = threadIdx.x >> 6;
            red2[w][0] = p0; red2[w][1] = p1; red2[w][2] = p2;
        }
    }
    __syncthreads();
    if (threadIdx.x < 3)
        out[g * 3 + threadIdx.x] = red2[0][threadIdx.x] + red2[1][threadIdx.x] + bc[threadIdx.x];
}

extern "C" void kernel_launch(void* const* d_in, const int* in_sizes, int n_in,
                              void* d_out, int out_size, void* d_ws, size_t ws_size,
                              hipStream_t stream) {
    (void)in_sizes; (void)n_in; (void)out_size; (void)ws_size;
    const int* edge_src = (const int*)d_in[0];
    const int* edge_dst = (const int*)d_in[1];
    const int* gids     = (const int*)d_in[2];
    const float* W1  = (const float*)d_in[3];
    const float* al1 = (const float*)d_in[4];
    const float* ar1 = (const float*)d_in[5];
    const float* b1  = (const float*)d_in[6];
    const float* W2  = (const float*)d_in[7];
    const float* al2 = (const float*)d_in[8];
    const float* ar2 = (const float*)d_in[9];
    const float* b2  = (const float*)d_in[10];
    const float* Wc  = (const float*)d_in[11];
    const float* bc  = (const float*)d_in[12];
    float* out = (float*)d_out;

    char* p = (char*)d_ws;
    auto alloc = [&](size_t bytes) -> char* {
        char* r = p;
        p += (bytes + 511) & ~(size_t)511;
        return r;
    };
    int*      dr    = (int*)alloc((size_t)NCLASS * N_NODES * 4);   // privatized counters
    int*      base  = (int*)alloc((size_t)NCLASS * N_NODES * 4);   // per-class CSR bases
    int*      rank  = (int*)alloc((size_t)N_EDGES * 4);            // per-edge within-class rank
    int*      offs  = (int*)alloc((size_t)(N_NODES + 1) * 4);
    int*      P     = (int*)alloc((size_t)SNB * 4);
    int*      P2    = (int*)alloc((size_t)SNB * 4);
    float*    scal  = (float*)alloc(64);
    int*      csr   = (int*)alloc((size_t)N_EDGES * 4);
    int*      deg   = (int*)alloc((size_t)N_NODES * 4);
    float*    t     = (float*)alloc((size_t)N_NODES * 4);
    float*    el2   = (float*)alloc((size_t)N_NODES * 4);
    float*    er2   = (float*)alloc((size_t)N_NODES * 4);
    unsigned* zb    = (unsigned*)alloc((size_t)N_NODES * 64 * 4);  // bf16x2 packed
    float*    h2    = (float*)alloc((size_t)N_NODES * HID * 4);

    hipMemsetAsync(dr, 0, (size_t)NCLASS * N_NODES * 4, stream);

    k_prep<<<1, 64, 0, stream>>>(W1, al1, ar1, scal);
    k_degrank<<<2048, 256, 0, stream>>>(edge_dst, dr, rank);
    k_sum<<<(N_NODES + 255) / 256, 256, 0, stream>>>(dr, deg);
    k_scan_part<<<SNB, 256, 0, stream>>>(deg, P);
    k_scan_p2<<<1, 64, 0, stream>>>(P, P2, offs);
    k_scan_final<<<SNB, 256, 0, stream>>>(deg, P2, offs);
    k_base<<<(N_NODES + 255) / 256, 256, 0, stream>>>(dr, offs, base);
    k_fill<<<2048, 256, 0, stream>>>(edge_src, edge_dst, base, rank, csr);
    k_l1<<<(N_NODES + 3) / 4, 256, 0, stream>>>(deg, offs, csr, scal, t);
    k_gemm<<<(N_NODES + 63) / 64, 256, 0, stream>>>(t, W1, b1, W2, al2, ar2, zb, el2, er2);
    k_l2f<<<(N_NODES + 3) / 4, 256, 0, stream>>>(offs, csr, el2, er2, zb, b2, h2);
    k_pool<<<N_GRAPHS, 1024, 0, stream>>>(gids, h2, Wc, bc, out);
}